// Round 6
// baseline (899.034 us; speedup 1.0000x reference)
//
#include <hip/hip_runtime.h>
#include <hip/hip_bf16.h>

#define B_   128
#define S_   512
#define H_   128
#define G_   512   // 4*H
#define EMB_ 128
#define NL_  9
#define CPW_ 2     // chains per workgroup

typedef __attribute__((ext_vector_type(8))) short bf16x8;
typedef __attribute__((ext_vector_type(4))) float f32x4;

// padded fragment slot: chunk stride 17 (16 rows + 1 pad)
#define FRAG(c, r) ((c) * 17 + (r))
// x ring: 16 slots x 16 chunks = chunks 0..255 ; h = chunks 256..271
#define NCHUNK 272

__device__ __forceinline__ float bfbits2f(short s) {
    unsigned int u = ((unsigned int)(unsigned short)s) << 16;
    return __builtin_bit_cast(float, u);
}
__device__ __forceinline__ short f2bf(float f) {
    unsigned int u = __builtin_bit_cast(unsigned int, f);
    u += 0x7FFFu + ((u >> 16) & 1u);
    return (short)(u >> 16);
}
__device__ __forceinline__ float sigm(float x) {
    return __builtin_amdgcn_rcpf(1.f + exp2f(-1.4426950408889634f * x));
}
__device__ __forceinline__ float tanh_(float x) {
    return 1.f - 2.f * __builtin_amdgcn_rcpf(1.f + exp2f(2.8853900817779268f * x));
}

// ---------------------------------------------------------------------------
// Fused LSTM + emissions. 128 wgs (64/dir), 2 chains, 512 thr (8 waves).
// Global ops are BATCHED so barriers rarely drain vmem:
//   - x-ring: 16 steps of x fragments in LDS; waves 4-7 stage 4 steps every
//     4th step (pre-fill 12 steps before loop).
//   - emissions: accumulated in a 16-slot LDS ring, flushed as contiguous
//     72-float blocks once per 8 steps.
// Per step (2 barriers): P1 = MFMA + gates + (staging|flush|emissions),
//                        P2 = gate nonlinearity + h -> LDS.
// ---------------------------------------------------------------------------
__global__ __launch_bounds__(512, 1)
void lstm_em_kernel(const int* __restrict__ seq, const float* __restrict__ emb,
                    const float* __restrict__ w_ih_f, const float* __restrict__ w_hh_f,
                    const float* __restrict__ b_ih_f, const float* __restrict__ b_hh_f,
                    const float* __restrict__ w_ih_b, const float* __restrict__ w_hh_b,
                    const float* __restrict__ b_ih_b, const float* __restrict__ b_hh_b,
                    const float* __restrict__ w_out,
                    float* __restrict__ em_f, float* __restrict__ em_b)
{
    __shared__ bf16x8 ldsA[NCHUNK * 17];    // 73,984 B
    __shared__ float  gatesL[CPW_ * G_];    // 4 KB [chain][col]
    __shared__ float  bsum[G_];             // 2 KB
    __shared__ int    ldsSeq[CPW_ * S_];    // 4 KB [chain][global t]
    __shared__ float  emL[2 * 16 * NL_];    // 1152 B [chain][slot][label]

    const int tid  = threadIdx.x;
    const int wv   = tid >> 6;
    const int n16  = tid & 15;
    const int quad = (tid & 63) >> 4;
    const int dir  = blockIdx.x >> 6;
    const int brow0 = (blockIdx.x & 63) * CPW_;

    const float* wih = dir ? w_ih_b : w_ih_f;
    const float* whh = dir ? w_hh_b : w_hh_f;
    const float* bih = dir ? b_ih_b : b_ih_f;
    const float* bhh = dir ? b_hh_b : b_hh_f;
    float* emdir = dir ? em_b : em_f;

    // B fragments: wave wv owns gate columns [wv*64, wv*64+64). f32 -> bf16.
    bf16x8 bfrag[4][8];
    const int nb = wv * 64 + n16;
#pragma unroll
    for (int nt = 0; nt < 4; nt++) {
        int n = nb + nt * 16;
#pragma unroll
        for (int ks = 0; ks < 8; ks++) {
            const float* p = (ks < 4) ? (wih + n * EMB_ + ks * 32 + quad * 8)
                                      : (whh + n * H_ + (ks - 4) * 32 + quad * 8);
            bf16x8 fr;
#pragma unroll
            for (int j = 0; j < 8; j++) fr[j] = f2bf(p[j]);
            bfrag[nt][ks] = fr;
        }
    }

    // emission lanes: waves 1-3, 8 lanes per (chain, label)
    const int eidx = tid - 64;
    const int eg = eidx >> 3, esub = eidx & 7;
    const bool edo = (tid >= 64) && (eg < 2 * NL_);
    const int ec = edo ? (eg / NL_) : 0;
    const int el = edo ? (eg % NL_) : 0;
    float wem[16];
    if (edo) {
#pragma unroll
        for (int k = 0; k < 16; k++)
            wem[k] = w_out[el * 256 + dir * 128 + esub * 16 + k];
    }

    bsum[tid] = bih[tid] + bhh[tid];
    {   bf16x8 z = {0,0,0,0,0,0,0,0};
        for (int i = tid; i < NCHUNK * 17; i += 512) ldsA[i] = z;
    }
    ldsSeq[tid]       = seq[brow0 * S_ + tid];
    ldsSeq[tid + 512] = seq[(brow0 + 1) * S_ + tid];
    __syncthreads();

    // pre-fill x ring slots 0..11 (2 chains x 12 steps = 24 rows)
    {
        int grp = tid >> 5, p = tid & 31;
#pragma unroll
        for (int r = 0; r < 2; r++) {
            int m = r * 16 + grp;
            if (m < 24) {
                int c = m / 12, j = m % 12;
                int tt = dir ? (S_ - 1 - j) : j;
                int tok = ldsSeq[c * S_ + tt];
                float4 x = *(const float4*)(emb + (size_t)tok * EMB_ + p * 4);
                short4 s;
                s.x = f2bf(x.x); s.y = f2bf(x.y); s.z = f2bf(x.z); s.w = f2bf(x.w);
                *(short4*)((short*)ldsA + FRAG(j * 16 + (p >> 1), c) * 8 + (p & 1) * 4) = s;
            }
        }
    }
    float cst = 0.f;
    const int uc = tid >> 7;     // update phase (tid<256)
    const int uj = tid & 127;
    __syncthreads();

    for (int t = 0; t < S_; t++) {
        // ---- P1 ----
        if ((t & 3) == 0 && tid >= 256) {   // stage x for steps t+12..t+15
            int g = (tid - 256) >> 5, p = tid & 31;
            int c = g >> 2, tp = t + 12 + (g & 3);
            if (tp < S_) {
                int tt = dir ? (S_ - 1 - tp) : tp;
                int tok = ldsSeq[c * S_ + tt];
                float4 x = *(const float4*)(emb + (size_t)tok * EMB_ + p * 4);
                short4 s;
                s.x = f2bf(x.x); s.y = f2bf(x.y); s.z = f2bf(x.z); s.w = f2bf(x.w);
                *(short4*)((short*)ldsA + FRAG((tp & 15) * 16 + (p >> 1), c) * 8 + (p & 1) * 4) = s;
            }
        }
        if ((t & 7) == 1 && t >= 9 && tid >= 256 && tid < 400) {  // flush block [t-9, t-2]
            int fl = tid - 256;          // 0..143
            int c = fl / 72, q = fl % 72;
            int t0 = t - 9;
            int base_g = dir ? (S_ - 8 - t0) : t0;   // 8-aligned global start
            float v = emL[c * 144 + ((base_g & 15) + q / 9) * NL_ + (q % 9)];
            emdir[((size_t)(brow0 + c) * S_ + base_g) * NL_ + q] = v;
        }
        if (edo && t > 0) {                 // emission for h of step t-1 -> emL
            int ttp = dir ? (S_ - t) : (t - 1);
            bf16x8 h0 = ldsA[FRAG(256 + esub * 2, ec)];
            bf16x8 h1 = ldsA[FRAG(257 + esub * 2, ec)];
            float d = 0.f;
#pragma unroll
            for (int k = 0; k < 8; k++) d += bfbits2f(h0[k]) * wem[k];
#pragma unroll
            for (int k = 0; k < 8; k++) d += bfbits2f(h1[k]) * wem[8 + k];
            d += __shfl_down(d, 4, 8);
            d += __shfl_down(d, 2, 8);
            d += __shfl_down(d, 1, 8);
            if (esub == 0) emL[ec * 144 + (ttp & 15) * NL_ + el] = d;
        }
        {   // MFMA: gates = [x_t | h] @ Wcat^T
            bf16x8 af[8];
            const int xb = (t & 15) * 16;
#pragma unroll
            for (int ks = 0; ks < 4; ks++) af[ks] = ldsA[FRAG(xb + ks * 4 + quad, n16)];
#pragma unroll
            for (int ks = 0; ks < 4; ks++) af[4 + ks] = ldsA[FRAG(256 + ks * 4 + quad, n16)];
#pragma unroll
            for (int nt = 0; nt < 4; nt++) {
                f32x4 acc = {0.f, 0.f, 0.f, 0.f};
#pragma unroll
                for (int ks = 0; ks < 8; ks++)
                    acc = __builtin_amdgcn_mfma_f32_16x16x32_bf16(af[ks], bfrag[nt][ks], acc, 0, 0, 0);
                if (quad == 0) {
                    int col = wv * 64 + nt * 16 + n16;
                    gatesL[col] = acc[0];
                    gatesL[G_ + col] = acc[1];
                }
            }
        }
        __syncthreads();

        // ---- P2: nonlinearity + state update; h -> LDS ----
        if (tid < CPW_ * H_) {
            float ip = gatesL[uc * G_ + uj]          + bsum[uj];
            float fp = gatesL[uc * G_ + H_ + uj]     + bsum[H_ + uj];
            float gp = gatesL[uc * G_ + 2 * H_ + uj] + bsum[2 * H_ + uj];
            float op = gatesL[uc * G_ + 3 * H_ + uj] + bsum[3 * H_ + uj];
            cst = sigm(fp) * cst + sigm(ip) * tanh_(gp);
            float hv = sigm(op) * tanh_(cst);
            ((short*)ldsA)[FRAG(256 + (uj >> 3), uc) * 8 + (uj & 7)] = f2bf(hv);
        }
        __syncthreads();
    }

    // final emission (h of step S-1)
    if (edo) {
        int ttp = dir ? 0 : (S_ - 1);
        bf16x8 h0 = ldsA[FRAG(256 + esub * 2, ec)];
        bf16x8 h1 = ldsA[FRAG(257 + esub * 2, ec)];
        float d = 0.f;
#pragma unroll
        for (int k = 0; k < 8; k++) d += bfbits2f(h0[k]) * wem[k];
#pragma unroll
        for (int k = 0; k < 8; k++) d += bfbits2f(h1[k]) * wem[8 + k];
        d += __shfl_down(d, 4, 8);
        d += __shfl_down(d, 2, 8);
        d += __shfl_down(d, 1, 8);
        if (esub == 0) emL[ec * 144 + (ttp & 15) * NL_ + el] = d;
    }
    __syncthreads();
    // final flush: block [S-8, S-1]
    if (tid >= 256 && tid < 400) {
        int fl = tid - 256;
        int c = fl / 72, q = fl % 72;
        int base_g = dir ? 0 : (S_ - 8);
        float v = emL[c * 144 + ((base_g & 15) + q / 9) * NL_ + (q % 9)];
        emdir[((size_t)(brow0 + c) * S_ + base_g) * NL_ + q] = v;
    }
}

// ---------------------------------------------------------------------------
// CRF: 7 batches per wave (9 lanes each). 19 wgs x 64 threads.
// ---------------------------------------------------------------------------
__global__ __launch_bounds__(64, 8)
void crf_kernel(const int* __restrict__ seq, const int* __restrict__ lab,
                const float* __restrict__ em_f, const float* __restrict__ em_b,
                const float* __restrict__ b_out,
                const float* __restrict__ start_t, const float* __restrict__ end_t,
                const float* __restrict__ trans, float* __restrict__ partial)
{
    const int lane = threadIdx.x;
    const int g = lane / 9;             // group within wave (g==7: idle lane 63)
    const int j = lane - g * 9;
    const int b = blockIdx.x * 7 + g;
    const bool act = (g < 7) && (b < B_);
    const int gb = g * 9;
    const float L2E = 1.4426950408889634f, LN2 = 0.6931471805599453f;

    // ---- numerator (9 lanes per batch, strided t) ----
    float np = 0.f; int cnt = 0;
    if (act) {
        for (int t = j; t < S_; t += 9) {
            int m = (seq[b * S_ + t] != 0);
            cnt += m;
            if (t >= 1 && m) {
                int lp = lab[b * S_ + t - 1], lc = lab[b * S_ + t];
                size_t ix = ((size_t)b * S_ + t) * NL_ + lc;
                np += trans[lp * NL_ + lc] + em_f[ix] + em_b[ix] + b_out[lc];
            }
        }
    }
    float nps = 0.f; int cnt_s = 0;
#pragma unroll
    for (int i = 0; i < 9; i++) {
        nps   += __shfl(np, gb + i, 64);
        cnt_s += __shfl(cnt, gb + i, 64);
    }
    float num = 0.f;
    if (act && j == 0) {
        int l0 = lab[b * S_];
        int ll = lab[b * S_ + cnt_s - 1];
        size_t i0 = (size_t)b * S_ * NL_ + l0;
        num = nps + start_t[l0] + em_f[i0] + em_b[i0] + b_out[l0] + end_t[ll];
    }

    // ---- denominator: 9-state logsumexp forward pass ----
    const int jj = act ? j : 0;
    const int bb = act ? b : 0;
    const float boj = b_out[jj];
    float Tc[NL_];
#pragma unroll
    for (int i = 0; i < NL_; i++) Tc[i] = trans[i * NL_ + jj];
    const size_t base = (size_t)bb * S_ * NL_;
    float sc = start_t[jj] + em_f[base + jj] + em_b[base + jj] + boj;
    float nf = em_f[base + NL_ + jj];
    float nb2 = em_b[base + NL_ + jj];
    int nm = seq[bb * S_ + 1];
    for (int t = 1; t < S_; t++) {
        float emv = nf + nb2 + boj;
        int msk = nm;
        if (t < S_ - 1) {
            size_t ix = base + (size_t)(t + 1) * NL_ + jj;
            nf  = em_f[ix];
            nb2 = em_b[ix];
            nm  = seq[bb * S_ + t + 1];
        }
        float a[NL_];
#pragma unroll
        for (int i = 0; i < NL_; i++) a[i] = __shfl(sc, gb + i, 64) + Tc[i];
        float m = a[0];
#pragma unroll
        for (int i = 1; i < NL_; i++) m = fmaxf(m, a[i]);
        float sum = 0.f;
#pragma unroll
        for (int i = 0; i < NL_; i++) sum += exp2f((a[i] - m) * L2E);
        float nxt = emv + m + LN2 * log2f(sum);
        sc = msk ? nxt : sc;
    }
    float v = sc + end_t[jj];
    float mm = -1e30f, av[NL_];
#pragma unroll
    for (int i = 0; i < NL_; i++) { float vi = __shfl(v, gb + i, 64); av[i] = vi; mm = fmaxf(mm, vi); }
    float ss = 0.f;
#pragma unroll
    for (int i = 0; i < NL_; i++) ss += exp2f((av[i] - mm) * L2E);
    if (act && j == 0) partial[b] = (mm + LN2 * log2f(ss)) - num;
}

__global__ __launch_bounds__(128)
void reduce_kernel(const float* __restrict__ partial, float* __restrict__ out)
{
    __shared__ float s[128];
    int tid = threadIdx.x;
    s[tid] = partial[tid];
    __syncthreads();
    for (int off = 64; off; off >>= 1) {
        if (tid < off) s[tid] += s[tid + off];
        __syncthreads();
    }
    if (tid == 0) out[0] = s[0];
}

extern "C" void kernel_launch(void* const* d_in, const int* in_sizes, int n_in,
                              void* d_out, int out_size, void* d_ws, size_t ws_size,
                              hipStream_t stream)
{
    const int* seq = (const int*)d_in[0];
    const int* lab = (const int*)d_in[1];
    const float* emb    = (const float*)d_in[2];
    const float* w_ih_f = (const float*)d_in[3];
    const float* w_hh_f = (const float*)d_in[4];
    const float* b_ih_f = (const float*)d_in[5];
    const float* b_hh_f = (const float*)d_in[6];
    const float* w_ih_b = (const float*)d_in[7];
    const float* w_hh_b = (const float*)d_in[8];
    const float* b_ih_b = (const float*)d_in[9];
    const float* b_hh_b = (const float*)d_in[10];
    const float* w_out  = (const float*)d_in[11];
    const float* b_out  = (const float*)d_in[12];
    const float* start_t = (const float*)d_in[13];
    const float* end_t   = (const float*)d_in[14];
    const float* trans   = (const float*)d_in[15];

    char* ws = (char*)d_ws;
    const size_t em_bytes = (size_t)B_ * S_ * NL_ * sizeof(float);
    float* em_f    = (float*)ws;
    float* em_b    = (float*)(ws + em_bytes);
    float* partial = (float*)(ws + 2 * em_bytes);

    lstm_em_kernel<<<dim3(128), dim3(512), 0, stream>>>(seq, emb,
        w_ih_f, w_hh_f, b_ih_f, b_hh_f, w_ih_b, w_hh_b, b_ih_b, b_hh_b,
        w_out, em_f, em_b);
    crf_kernel<<<dim3((B_ + 6) / 7), dim3(64), 0, stream>>>(seq, lab, em_f, em_b, b_out,
        start_t, end_t, trans, partial);
    reduce_kernel<<<dim3(1), dim3(128), 0, stream>>>(partial, (float*)d_out);
}